// Round 1
// baseline (10931.738 us; speedup 1.0000x reference)
//
#include <hip/hip_runtime.h>
#include <hip/hip_bf16.h>

typedef __bf16 bf16x8 __attribute__((ext_vector_type(8)));
typedef __bf16 bf16x4 __attribute__((ext_vector_type(4)));
typedef float  f32x4  __attribute__((ext_vector_type(4)));

#define S_LEN  256
#define BATCH  16
#define EDIM   512
#define HDIM   512
#define VOCAB  32000
#define G4     2048          // 4*H
#define M_ROWS 4096          // S*B
#define LSTM_WGS 128

// ------- ws layout (bytes) -------
#define OFF_H     0                         // float[2][16][512] = 65536 (double-buffered h)
#define OFF_BAR   65536                     // int barrier counter (128B pad)
#define OFF_BIAS  65664                     // float[2048] = b_ih + b_hh
#define OFF_X     73856                     // bf16[4096*512] gathered embeddings
#define OFF_WIH   (OFF_X + 4194304)         // bf16[2048*512]
#define OFF_WLIN  (OFF_WIH + 2097152)       // bf16[32000*512]
#define OFF_XP    (OFF_WLIN + 32768000)     // float[4096*2048]
#define OFF_HS    (OFF_XP + 33554432)       // bf16[4096*512]
// total = 76,882,048 bytes

// ---------------- prep kernels ----------------
__global__ __launch_bounds__(256) void k_gather_cast_x(
    const int* __restrict__ tok, const float* __restrict__ embed, __bf16* __restrict__ xb) {
  int i = blockIdx.x * blockDim.x + threadIdx.x;          // over 4096*128 float4 chunks
  const int total = M_ROWS * (EDIM / 4);
  for (; i < total; i += gridDim.x * blockDim.x) {
    int m = i >> 7, c = i & 127;
    int t = tok[m];
    float4 v = ((const float4*)(embed + (size_t)t * EDIM))[c];
    bf16x4 o = { (__bf16)v.x, (__bf16)v.y, (__bf16)v.z, (__bf16)v.w };
    ((bf16x4*)(xb + (size_t)m * EDIM))[c] = o;
  }
}

__global__ __launch_bounds__(256) void k_cast(
    const float* __restrict__ src, __bf16* __restrict__ dst, int n4) {
  int i = blockIdx.x * blockDim.x + threadIdx.x;
  for (; i < n4; i += gridDim.x * blockDim.x) {
    float4 v = ((const float4*)src)[i];
    bf16x4 o = { (__bf16)v.x, (__bf16)v.y, (__bf16)v.z, (__bf16)v.w };
    ((bf16x4*)dst)[i] = o;
  }
}

__global__ __launch_bounds__(256) void k_bias(
    const float* __restrict__ b_ih, const float* __restrict__ b_hh, float* __restrict__ bb) {
  int i = blockIdx.x * blockDim.x + threadIdx.x;
  if (i < G4) bb[i] = b_ih[i] + b_hh[i];
}

// ---------------- bf16 MFMA GEMM: D[M,N] = A[M,K] * B[N,K]^T + bias[N] ----------------
// 64x64 tile, BK=64, 4 waves (2x2), each wave 32x32 via 2x2 16x16 frags.
__global__ __launch_bounds__(256) void k_gemm(
    const __bf16* __restrict__ A, const __bf16* __restrict__ B,
    float* __restrict__ D, const float* __restrict__ bias,
    int M, int N, int K) {
  __shared__ __align__(16) __bf16 As[64][72];   // +8 bf16 pad -> 2-way max on frag reads
  __shared__ __align__(16) __bf16 Bs[64][72];
  const int tid  = threadIdx.x;
  const int m0   = blockIdx.y * 64, n0 = blockIdx.x * 64;
  const int wave = tid >> 6, lane = tid & 63;
  const int wm   = (wave >> 1) * 32, wn = (wave & 1) * 32;
  const int lrow = lane & 15;
  const int kb   = (lane >> 4) * 8;             // per-lane contiguous-8 K offset
  f32x4 acc[2][2];
  #pragma unroll
  for (int i = 0; i < 2; ++i)
    #pragma unroll
    for (int j = 0; j < 2; ++j) { acc[i][j][0]=0.f; acc[i][j][1]=0.f; acc[i][j][2]=0.f; acc[i][j][3]=0.f; }

  const int lr = tid >> 3, ls = tid & 7;        // staging: 32 rows x 8 16B-segs, x2 passes
  for (int k0 = 0; k0 < K; k0 += 64) {
    const __bf16* Ab = A + (size_t)(m0 + lr) * K + k0 + ls * 8;
    *(bf16x8*)&As[lr][ls * 8]      = *(const bf16x8*)Ab;
    *(bf16x8*)&As[lr + 32][ls * 8] = *(const bf16x8*)(Ab + (size_t)32 * K);
    const __bf16* Bb = B + (size_t)(n0 + lr) * K + k0 + ls * 8;
    *(bf16x8*)&Bs[lr][ls * 8]      = *(const bf16x8*)Bb;
    *(bf16x8*)&Bs[lr + 32][ls * 8] = *(const bf16x8*)(Bb + (size_t)32 * K);
    __syncthreads();
    #pragma unroll
    for (int ks = 0; ks < 2; ++ks) {
      int kk = ks * 32 + kb;
      bf16x8 a0 = *(const bf16x8*)&As[wm + lrow][kk];
      bf16x8 a1 = *(const bf16x8*)&As[wm + 16 + lrow][kk];
      bf16x8 b0 = *(const bf16x8*)&Bs[wn + lrow][kk];
      bf16x8 b1 = *(const bf16x8*)&Bs[wn + 16 + lrow][kk];
      acc[0][0] = __builtin_amdgcn_mfma_f32_16x16x32_bf16(a0, b0, acc[0][0], 0, 0, 0);
      acc[0][1] = __builtin_amdgcn_mfma_f32_16x16x32_bf16(a0, b1, acc[0][1], 0, 0, 0);
      acc[1][0] = __builtin_amdgcn_mfma_f32_16x16x32_bf16(a1, b0, acc[1][0], 0, 0, 0);
      acc[1][1] = __builtin_amdgcn_mfma_f32_16x16x32_bf16(a1, b1, acc[1][1], 0, 0, 0);
    }
    __syncthreads();
  }
  // epilogue: D row = (lane>>4)*4 + reg, col = lane&15  [verified m89/m91 mapping]
  const int col = lane & 15;
  const int rbase = (lane >> 4) * 4;
  #pragma unroll
  for (int mi = 0; mi < 2; ++mi)
    #pragma unroll
    for (int ni = 0; ni < 2; ++ni) {
      int nn = n0 + wn + ni * 16 + col;
      float bv = bias[nn];
      #pragma unroll
      for (int rr = 0; rr < 4; ++rr) {
        int mm = m0 + wm + mi * 16 + rbase + rr;
        D[(size_t)mm * N + nn] = acc[mi][ni][rr] + bv;
      }
    }
}

// ---------------- persistent LSTM ----------------
// 128 WGs; WG wg owns cell indices wg*4..wg*4+3 (16 W_hh rows resident in LDS).
// h double-buffered in global; one fence+atomic barrier per step.
__global__ __launch_bounds__(256) void k_lstm(
    const float* __restrict__ xp, const float* __restrict__ Whh,
    float* __restrict__ h_buf, int* __restrict__ bar, __bf16* __restrict__ hs) {
  __shared__ __align__(16) float w_lds[16][516];  // pad 4 -> 2-way max
  __shared__ float g_lds[16][16];                 // gates [row r][batch b]
  const int tid = threadIdx.x;
  const int wg  = blockIdx.x;
  const int nwg = gridDim.x;
  {  // stage this WG's 16 weight rows (once)
    int r = tid >> 4, seg = tid & 15;             // 16 thr/row, 32 f32 each
    int grow = (r >> 2) * 512 + wg * 4 + (r & 3);
    const float4* src = (const float4*)(Whh + (size_t)grow * 512 + seg * 32);
    float4* dst = (float4*)&w_lds[r][seg * 32];
    #pragma unroll
    for (int q = 0; q < 8; ++q) dst[q] = src[q];
  }
  __syncthreads();
  const int b = tid & 15, r = tid >> 4;           // one dot per thread
  const int grow = (r >> 2) * 512 + wg * 4 + (r & 3);
  const int jl = tid >> 4;                        // update threads (tid<64): jl 0..3
  float c_reg = 0.f;

  for (int s = 0; s < S_LEN; ++s) {
    const float4* hb = (const float4*)(h_buf + (s & 1) * 8192 + b * 512);
    const float4* wr = (const float4*)&w_lds[r][0];
    float acc = 0.f;
    #pragma unroll 8
    for (int q = 0; q < 128; ++q) {
      float4 hv = hb[q], wv = wr[q];
      acc = fmaf(hv.x, wv.x, acc); acc = fmaf(hv.y, wv.y, acc);
      acc = fmaf(hv.z, wv.z, acc); acc = fmaf(hv.w, wv.w, acc);
    }
    acc += xp[(size_t)(s * BATCH + b) * G4 + grow];
    g_lds[r][b] = acc;
    __syncthreads();
    if (tid < 64) {
      float ig = g_lds[0 + jl][b], fg = g_lds[4 + jl][b],
            gg = g_lds[8 + jl][b], og = g_lds[12 + jl][b];
      float si = 1.f / (1.f + __expf(-ig));
      float sf = 1.f / (1.f + __expf(-fg));
      float so = 1.f / (1.f + __expf(-og));
      float tg = tanhf(gg);
      c_reg = sf * c_reg + si * tg;
      float h = so * tanhf(c_reg);
      h_buf[((s + 1) & 1) * 8192 + b * 512 + wg * 4 + jl] = h;
      hs[(size_t)(s * BATCH + b) * HDIM + wg * 4 + jl] = (__bf16)h;
    }
    __threadfence();            // push h writes to device coherence point
    __syncthreads();
    if (tid == 0) {
      __hip_atomic_fetch_add(bar, 1, __ATOMIC_RELEASE, __HIP_MEMORY_SCOPE_AGENT);
      const int target = nwg * (s + 1);
      while (__hip_atomic_load(bar, __ATOMIC_ACQUIRE, __HIP_MEMORY_SCOPE_AGENT) < target) {}
    }
    __syncthreads();
    __threadfence();            // acquire side: invalidate stale L1/L2 before reading new h
  }
}

// ---------------- in-place log_softmax over V=32000 ----------------
__global__ __launch_bounds__(256) void k_logsm(float* __restrict__ out) {
  const int row = blockIdx.x;
  float* p = out + (size_t)row * VOCAB;
  const int tid = threadIdx.x;
  float m = -INFINITY, ssum = 0.f;
  for (int i = tid; i < VOCAB / 4; i += 256) {
    float4 v = ((const float4*)p)[i];
    float nm = fmaxf(fmaxf(m, v.x), fmaxf(fmaxf(v.y, v.z), v.w));
    if (nm > m) { ssum *= __expf(m - nm); m = nm; }
    ssum += __expf(v.x - m) + __expf(v.y - m) + __expf(v.z - m) + __expf(v.w - m);
  }
  #pragma unroll
  for (int off = 32; off > 0; off >>= 1) {
    float mo = __shfl_down(m, off);
    float so = __shfl_down(ssum, off);
    float nm = fmaxf(m, mo);
    ssum = ssum * __expf(m - nm) + so * __expf(mo - nm);
    m = nm;
  }
  __shared__ float sm[4], ss[4], lse_s;
  int wid = tid >> 6;
  if ((tid & 63) == 0) { sm[wid] = m; ss[wid] = ssum; }
  __syncthreads();
  if (tid == 0) {
    float M = sm[0], Ssum = ss[0];
    #pragma unroll
    for (int w = 1; w < 4; ++w) {
      float nm = fmaxf(M, sm[w]);
      Ssum = Ssum * __expf(M - nm) + ss[w] * __expf(sm[w] - nm);
      M = nm;
    }
    lse_s = M + logf(Ssum);
  }
  __syncthreads();
  const float lse = lse_s;
  for (int i = tid; i < VOCAB / 4; i += 256) {
    float4 v = ((const float4*)p)[i];
    v.x -= lse; v.y -= lse; v.z -= lse; v.w -= lse;
    ((float4*)p)[i] = v;
  }
}

extern "C" void kernel_launch(void* const* d_in, const int* in_sizes, int n_in,
                              void* d_out, int out_size, void* d_ws, size_t ws_size,
                              hipStream_t stream) {
  const int*   tok   = (const int*)d_in[0];
  // d_in[1] = input_lengths: unused by the reference
  const float* embed = (const float*)d_in[2];
  const float* W_ih  = (const float*)d_in[3];
  const float* W_hh  = (const float*)d_in[4];
  const float* b_ih  = (const float*)d_in[5];
  const float* b_hh  = (const float*)d_in[6];
  const float* W_lin = (const float*)d_in[7];
  const float* b_lin = (const float*)d_in[8];
  float* out = (float*)d_out;
  char*  ws  = (char*)d_ws;

  float*  h_buf    = (float*)(ws + OFF_H);
  int*    bar      = (int*)(ws + OFF_BAR);
  float*  bias_sum = (float*)(ws + OFF_BIAS);
  __bf16* xb       = (__bf16*)(ws + OFF_X);
  __bf16* wihb     = (__bf16*)(ws + OFF_WIH);
  __bf16* wlinb    = (__bf16*)(ws + OFF_WLIN);
  float*  xp       = (float*)(ws + OFF_XP);
  __bf16* hs       = (__bf16*)(ws + OFF_HS);

  // zero h double-buffer + barrier counter (required every replay)
  hipMemsetAsync(ws, 0, OFF_BIAS, stream);

  k_gather_cast_x<<<2048, 256, 0, stream>>>(tok, embed, xb);
  k_cast<<<1024, 256, 0, stream>>>(W_ih, wihb, G4 * EDIM / 4);
  k_cast<<<2048, 256, 0, stream>>>(W_lin, wlinb, VOCAB * HDIM / 4);
  k_bias<<<8, 256, 0, stream>>>(b_ih, b_hh, bias_sum);

  k_gemm<<<dim3(G4 / 64, M_ROWS / 64), 256, 0, stream>>>(xb, wihb, xp, bias_sum, M_ROWS, G4, EDIM);
  k_lstm<<<LSTM_WGS, 256, 0, stream>>>(xp, W_hh, h_buf, bar, hs);
  k_gemm<<<dim3(VOCAB / 64, M_ROWS / 64), 256, 0, stream>>>(hs, wlinb, out, b_lin, M_ROWS, VOCAB, HDIM);
  k_logsm<<<4096, 256, 0, stream>>>(out);
}

// Round 2
// 2214.840 us; speedup vs baseline: 4.9357x; 4.9357x over previous
//
#include <hip/hip_runtime.h>
#include <hip/hip_bf16.h>

typedef __bf16 bf16x8 __attribute__((ext_vector_type(8)));
typedef __bf16 bf16x4 __attribute__((ext_vector_type(4)));
typedef float  f32x4  __attribute__((ext_vector_type(4)));

#define S_LEN  256
#define BATCH  16
#define EDIM   512
#define HDIM   512
#define VOCAB  32000
#define G4     2048          // 4*H
#define M_ROWS 4096          // S*B
#define NWG_LSTM 32
#define FLAG_STRIDE 32       // ints -> 128B per flag slot

// ------- ws layout (bytes) -------
#define OFF_FLAGS 0                         // int[32*32] barrier flags
#define OFF_BIAS  4096                      // float[2048] = b_ih + b_hh
#define OFF_X     12288                     // bf16[4096*512] gathered embeddings
#define OFF_WIH   (OFF_X + 4194304)         // bf16[2048*512]
#define OFF_WLIN  (OFF_WIH + 2097152)       // bf16[32000*512]
#define OFF_XP    (OFF_WLIN + 32768000)     // float[4096*2048]
#define OFF_HS    (OFF_XP + 33554432)       // bf16[257*16*512]; slab 0 zeroed (h_0)
// total = 76,836,864 bytes

// ---------------- prep kernels ----------------
__global__ __launch_bounds__(256) void k_gather_cast_x(
    const int* __restrict__ tok, const float* __restrict__ embed, __bf16* __restrict__ xb) {
  int i = blockIdx.x * blockDim.x + threadIdx.x;          // over 4096*128 float4 chunks
  const int total = M_ROWS * (EDIM / 4);
  for (; i < total; i += gridDim.x * blockDim.x) {
    int m = i >> 7, c = i & 127;
    int t = tok[m];
    float4 v = ((const float4*)(embed + (size_t)t * EDIM))[c];
    bf16x4 o = { (__bf16)v.x, (__bf16)v.y, (__bf16)v.z, (__bf16)v.w };
    ((bf16x4*)(xb + (size_t)m * EDIM))[c] = o;
  }
}

__global__ __launch_bounds__(256) void k_cast(
    const float* __restrict__ src, __bf16* __restrict__ dst, int n4) {
  int i = blockIdx.x * blockDim.x + threadIdx.x;
  for (; i < n4; i += gridDim.x * blockDim.x) {
    float4 v = ((const float4*)src)[i];
    bf16x4 o = { (__bf16)v.x, (__bf16)v.y, (__bf16)v.z, (__bf16)v.w };
    ((bf16x4*)dst)[i] = o;
  }
}

__global__ __launch_bounds__(256) void k_bias(
    const float* __restrict__ b_ih, const float* __restrict__ b_hh, float* __restrict__ bb) {
  int i = blockIdx.x * blockDim.x + threadIdx.x;
  if (i < G4) bb[i] = b_ih[i] + b_hh[i];
}

// ---------------- bf16 MFMA GEMM: D[M,N] = A[M,K] * B[N,K]^T + bias[N] ----------------
// 64x64 tile, BK=64, 4 waves (2x2), each wave 32x32 via 2x2 16x16 frags.
__global__ __launch_bounds__(256) void k_gemm(
    const __bf16* __restrict__ A, const __bf16* __restrict__ B,
    float* __restrict__ D, const float* __restrict__ bias,
    int M, int N, int K) {
  __shared__ __align__(16) __bf16 As[64][72];   // +8 bf16 pad -> 2-way max on frag reads
  __shared__ __align__(16) __bf16 Bs[64][72];
  const int tid  = threadIdx.x;
  const int m0   = blockIdx.y * 64, n0 = blockIdx.x * 64;
  const int wave = tid >> 6, lane = tid & 63;
  const int wm   = (wave >> 1) * 32, wn = (wave & 1) * 32;
  const int lrow = lane & 15;
  const int kb   = (lane >> 4) * 8;             // per-lane contiguous-8 K offset
  f32x4 acc[2][2];
  #pragma unroll
  for (int i = 0; i < 2; ++i)
    #pragma unroll
    for (int j = 0; j < 2; ++j) { acc[i][j][0]=0.f; acc[i][j][1]=0.f; acc[i][j][2]=0.f; acc[i][j][3]=0.f; }

  const int lr = tid >> 3, ls = tid & 7;        // staging: 32 rows x 8 16B-segs, x2 passes
  for (int k0 = 0; k0 < K; k0 += 64) {
    const __bf16* Ab = A + (size_t)(m0 + lr) * K + k0 + ls * 8;
    *(bf16x8*)&As[lr][ls * 8]      = *(const bf16x8*)Ab;
    *(bf16x8*)&As[lr + 32][ls * 8] = *(const bf16x8*)(Ab + (size_t)32 * K);
    const __bf16* Bb = B + (size_t)(n0 + lr) * K + k0 + ls * 8;
    *(bf16x8*)&Bs[lr][ls * 8]      = *(const bf16x8*)Bb;
    *(bf16x8*)&Bs[lr + 32][ls * 8] = *(const bf16x8*)(Bb + (size_t)32 * K);
    __syncthreads();
    #pragma unroll
    for (int ks = 0; ks < 2; ++ks) {
      int kk = ks * 32 + kb;
      bf16x8 a0 = *(const bf16x8*)&As[wm + lrow][kk];
      bf16x8 a1 = *(const bf16x8*)&As[wm + 16 + lrow][kk];
      bf16x8 b0 = *(const bf16x8*)&Bs[wn + lrow][kk];
      bf16x8 b1 = *(const bf16x8*)&Bs[wn + 16 + lrow][kk];
      acc[0][0] = __builtin_amdgcn_mfma_f32_16x16x32_bf16(a0, b0, acc[0][0], 0, 0, 0);
      acc[0][1] = __builtin_amdgcn_mfma_f32_16x16x32_bf16(a0, b1, acc[0][1], 0, 0, 0);
      acc[1][0] = __builtin_amdgcn_mfma_f32_16x16x32_bf16(a1, b0, acc[1][0], 0, 0, 0);
      acc[1][1] = __builtin_amdgcn_mfma_f32_16x16x32_bf16(a1, b1, acc[1][1], 0, 0, 0);
    }
    __syncthreads();
  }
  // epilogue: D row = (lane>>4)*4 + reg, col = lane&15  [verified m89/m91 mapping]
  const int col = lane & 15;
  const int rbase = (lane >> 4) * 4;
  #pragma unroll
  for (int mi = 0; mi < 2; ++mi)
    #pragma unroll
    for (int ni = 0; ni < 2; ++ni) {
      int nn = n0 + wn + ni * 16 + col;
      float bv = bias[nn];
      #pragma unroll
      for (int rr = 0; rr < 4; ++rr) {
        int mm = m0 + wm + mi * 16 + rbase + rr;
        D[(size_t)mm * N + nn] = acc[mi][ni][rr] + bv;
      }
    }
}

// ---------------- persistent MFMA LSTM ----------------
// 32 WGs x 4 waves = 128 waves. Wave W owns cells W*4..W*4+3, i.e. gate rows
// {g*512 + W*4 + cl : g=0..3, cl=0..3} -> 16 MFMA B-cols, W_hh frags in VGPRs.
// h state lives in hs_full[s][batch][cell] (bf16); slab s read as A-frags,
// slab s+1 written by the update. Flag-array barrier, one slot per WG.
__global__ __launch_bounds__(256) void k_lstm2(
    const float* __restrict__ xp, const float* __restrict__ Whh,
    __bf16* __restrict__ hs_full, int* __restrict__ flags) {
  const int tid  = threadIdx.x;
  const int lane = tid & 63;
  const int wv   = tid >> 6;               // 0..3
  const int W    = blockIdx.x * 4 + wv;    // 0..127
  const int c0   = W * 4;                  // first cell owned by this wave
  const int nl   = lane & 15;              // MFMA col (n_local) / A row (batch)
  const int g    = nl >> 2, cl = nl & 3;
  const int Grow = g * 512 + c0 + cl;      // gate row in [0,2048)
  const int kb   = (lane >> 4) * 8;        // per-lane K offset
  const int B0   = (lane >> 4) * 4;        // batch base of acc regs

  // ---- B-frags: W_hh[Grow][k], fp32 -> bf16, 64 VGPRs, loaded once ----
  bf16x8 bfrag[16];
  #pragma unroll
  for (int kk = 0; kk < 16; ++kk) {
    const float4* src = (const float4*)(Whh + (size_t)Grow * 512 + kk * 32 + kb);
    float4 w0 = src[0], w1 = src[1];
    bf16x8 t = { (__bf16)w0.x, (__bf16)w0.y, (__bf16)w0.z, (__bf16)w0.w,
                 (__bf16)w1.x, (__bf16)w1.y, (__bf16)w1.z, (__bf16)w1.w };
    bfrag[kk] = t;
  }

  float c_reg[4] = {0.f, 0.f, 0.f, 0.f};
  f32x4 xq;                                // xp[s][B0+r][Grow], prefetched
  #pragma unroll
  for (int r = 0; r < 4; ++r) xq[r] = xp[(size_t)(B0 + r) * G4 + Grow];

  for (int s = 0; s < S_LEN; ++s) {
    // A-frags: h_s[batch=nl][k], 16B loads (L2/L3-resident 16KB)
    const __bf16* hrow = hs_full + (size_t)s * 8192 + nl * 512 + kb;
    bf16x8 afrag[16];
    #pragma unroll
    for (int kk = 0; kk < 16; ++kk)
      afrag[kk] = *(const bf16x8*)(hrow + kk * 32);

    f32x4 acc0 = xq;                       // C-in = input projection (incl. biases)
    f32x4 acc1 = {0.f, 0.f, 0.f, 0.f};
    #pragma unroll
    for (int kk = 0; kk < 16; kk += 2) {
      acc0 = __builtin_amdgcn_mfma_f32_16x16x32_bf16(afrag[kk],     bfrag[kk],     acc0, 0, 0, 0);
      acc1 = __builtin_amdgcn_mfma_f32_16x16x32_bf16(afrag[kk + 1], bfrag[kk + 1], acc1, 0, 0, 0);
    }

    // prefetch next step's xp while MFMA drains
    if (s + 1 < S_LEN) {
      const float* nx = xp + ((size_t)(s + 1) * BATCH + B0) * G4 + Grow;
      #pragma unroll
      for (int r = 0; r < 4; ++r) xq[r] = nx[(size_t)r * G4];
    }

    f32x4 gates;
    #pragma unroll
    for (int r = 0; r < 4; ++r) gates[r] = acc0[r] + acc1[r];

    // redistribute: this lane takes i,f,g,o of cell c0+(lane&3), batches B0..B0+3
    const int lbase = (lane & 48) | (lane & 3);
    float hnew[4];
    #pragma unroll
    for (int r = 0; r < 4; ++r) {
      float ig = __shfl(gates[r], lbase + 0);
      float fg = __shfl(gates[r], lbase + 4);
      float gg = __shfl(gates[r], lbase + 8);
      float og = __shfl(gates[r], lbase + 12);
      float si = 1.f / (1.f + __expf(-ig));
      float sf = 1.f / (1.f + __expf(-fg));
      float so = 1.f / (1.f + __expf(-og));
      float ag = fabsf(gg), eg = __expf(-2.f * ag);
      float tg = __builtin_copysignf((1.f - eg) / (1.f + eg), gg);
      float c  = sf * c_reg[r] + si * tg;
      c_reg[r] = c;
      float ac = fabsf(c), ec = __expf(-2.f * ac);
      float tc = __builtin_copysignf((1.f - ec) / (1.f + ec), c);
      hnew[r]  = so * tc;
    }
    if ((lane & 12) == 0) {                // 16 writer lanes: cell c0+(lane&3)
      __bf16* dst = hs_full + (size_t)(s + 1) * 8192 + (size_t)B0 * 512 + c0 + (lane & 3);
      #pragma unroll
      for (int r = 0; r < 4; ++r) dst[(size_t)r * 512] = (__bf16)hnew[r];
    }

    __syncthreads();                       // drains this WG's h stores (vmcnt 0)
    if (wv == 0) {
      if (lane == 0)
        __hip_atomic_store(flags + blockIdx.x * FLAG_STRIDE, s + 1,
                           __ATOMIC_RELEASE, __HIP_MEMORY_SCOPE_AGENT);
      if (lane < NWG_LSTM) {
        while (__hip_atomic_load(flags + lane * FLAG_STRIDE,
                                 __ATOMIC_ACQUIRE, __HIP_MEMORY_SCOPE_AGENT) < s + 1) {}
      }
    }
    __syncthreads();
  }
}

// ---------------- in-place log_softmax over V=32000 ----------------
__global__ __launch_bounds__(256) void k_logsm(float* __restrict__ out) {
  const int row = blockIdx.x;
  float* p = out + (size_t)row * VOCAB;
  const int tid = threadIdx.x;
  float m = -INFINITY, ssum = 0.f;
  for (int i = tid; i < VOCAB / 4; i += 256) {
    float4 v = ((const float4*)p)[i];
    float nm = fmaxf(fmaxf(m, v.x), fmaxf(fmaxf(v.y, v.z), v.w));
    if (nm > m) { ssum *= __expf(m - nm); m = nm; }
    ssum += __expf(v.x - m) + __expf(v.y - m) + __expf(v.z - m) + __expf(v.w - m);
  }
  #pragma unroll
  for (int off = 32; off > 0; off >>= 1) {
    float mo = __shfl_down(m, off);
    float so = __shfl_down(ssum, off);
    float nm = fmaxf(m, mo);
    ssum = ssum * __expf(m - nm) + so * __expf(mo - nm);
    m = nm;
  }
  __shared__ float sm[4], ss[4], lse_s;
  int wid = tid >> 6;
  if ((tid & 63) == 0) { sm[wid] = m; ss[wid] = ssum; }
  __syncthreads();
  if (tid == 0) {
    float M = sm[0], Ssum = ss[0];
    #pragma unroll
    for (int w = 1; w < 4; ++w) {
      float nm = fmaxf(M, sm[w]);
      Ssum = Ssum * __expf(M - nm) + ss[w] * __expf(sm[w] - nm);
      M = nm;
    }
    lse_s = M + logf(Ssum);
  }
  __syncthreads();
  const float lse = lse_s;
  for (int i = tid; i < VOCAB / 4; i += 256) {
    float4 v = ((const float4*)p)[i];
    v.x -= lse; v.y -= lse; v.z -= lse; v.w -= lse;
    ((float4*)p)[i] = v;
  }
}

extern "C" void kernel_launch(void* const* d_in, const int* in_sizes, int n_in,
                              void* d_out, int out_size, void* d_ws, size_t ws_size,
                              hipStream_t stream) {
  const int*   tok   = (const int*)d_in[0];
  // d_in[1] = input_lengths: unused by the reference
  const float* embed = (const float*)d_in[2];
  const float* W_ih  = (const float*)d_in[3];
  const float* W_hh  = (const float*)d_in[4];
  const float* b_ih  = (const float*)d_in[5];
  const float* b_hh  = (const float*)d_in[6];
  const float* W_lin = (const float*)d_in[7];
  const float* b_lin = (const float*)d_in[8];
  float* out = (float*)d_out;
  char*  ws  = (char*)d_ws;

  int*    flags    = (int*)(ws + OFF_FLAGS);
  float*  bias_sum = (float*)(ws + OFF_BIAS);
  __bf16* xb       = (__bf16*)(ws + OFF_X);
  __bf16* wihb     = (__bf16*)(ws + OFF_WIH);
  __bf16* wlinb    = (__bf16*)(ws + OFF_WLIN);
  float*  xp       = (float*)(ws + OFF_XP);
  __bf16* hs_full  = (__bf16*)(ws + OFF_HS);

  // zero barrier flags + h_0 slab (required every replay; both small)
  hipMemsetAsync(ws + OFF_FLAGS, 0, 4096, stream);
  hipMemsetAsync(ws + OFF_HS, 0, BATCH * HDIM * sizeof(__bf16), stream);

  k_gather_cast_x<<<2048, 256, 0, stream>>>(tok, embed, xb);
  k_cast<<<1024, 256, 0, stream>>>(W_ih, wihb, G4 * EDIM / 4);
  k_cast<<<2048, 256, 0, stream>>>(W_lin, wlinb, VOCAB * HDIM / 4);
  k_bias<<<8, 256, 0, stream>>>(b_ih, b_hh, bias_sum);

  k_gemm<<<dim3(G4 / 64, M_ROWS / 64), 256, 0, stream>>>(xb, wihb, xp, bias_sum, M_ROWS, G4, EDIM);
  k_lstm2<<<NWG_LSTM, 256, 0, stream>>>(xp, W_hh, hs_full, flags);
  k_gemm<<<dim3(VOCAB / 64, M_ROWS / 64), 256, 0, stream>>>(hs_full + BATCH * HDIM, wlinb, out, b_lin, M_ROWS, VOCAB, HDIM);
  k_logsm<<<4096, 256, 0, stream>>>(out);
}